// Round 1
// baseline (88.679 us; speedup 1.0000x reference)
//
#include <hip/hip_runtime.h>

// out[b, t, w, c] = x[b, t + w - 9, c] (zero outside [0, T)), x: [32, 4096, 30] f32
// Flattened per (b,t): out row of W*C = 570 contiguous floats equals the
// contiguous x span starting at (t-9)*C, zero-padded at batch edges.

constexpr int B = 32;
constexpr int T = 4096;           // power of 2
constexpr int C = 30;
constexpr int W = 19;
constexpr int PAD = W / 2;        // 9
constexpr int ROW = W * C;        // 570 floats per output row
constexpr int ROW2 = ROW / 2;     // 285 float2 units per row
constexpr int TC = T * C;         // 122880 elements per batch of x
constexpr unsigned TOTAL2 = (unsigned)B * T * ROW2;  // 37,324,800 float2 units

__global__ __launch_bounds__(256)
void OverlapTimeWindowLayer_kernel(const float* __restrict__ x,
                                   float2* __restrict__ out) {
    const unsigned stride = gridDim.x * blockDim.x;
    for (unsigned v = blockIdx.x * blockDim.x + threadIdx.x; v < TOTAL2; v += stride) {
        // Decompose: v = row * ROW2 + j2 ; row = b*T + t
        unsigned row = v / ROW2;                 // magic-mul div by 285
        int      j2  = (int)(v - row * ROW2);
        int      b   = (int)(row >> 12);         // / T
        int      t   = (int)(row & (T - 1));     // % T
        // Source element offset within batch b (can be negative near edges).
        // Both elements of the float2 share the same (w) source time step,
        // so one range check covers both.
        int s = (t - PAD) * C + 2 * j2;
        float2 val = make_float2(0.0f, 0.0f);
        if (s >= 0 && s < TC) {
            val = *reinterpret_cast<const float2*>(x + (unsigned)b * TC + (unsigned)s);
        }
        out[v] = val;
    }
}

extern "C" void kernel_launch(void* const* d_in, const int* in_sizes, int n_in,
                              void* d_out, int out_size, void* d_ws, size_t ws_size,
                              hipStream_t stream) {
    const float* x = (const float*)d_in[0];
    float2* out = (float2*)d_out;
    const int block = 256;
    const int grid = 2048;  // grid-stride; ~71 float2 units per thread
    OverlapTimeWindowLayer_kernel<<<grid, block, 0, stream>>>(x, out);
}

// Round 3
// 63.427 us; speedup vs baseline: 1.3981x; 1.3981x over previous
//
#include <hip/hip_runtime.h>

// out[b, t, w, c] = x[b, t + w - 9, c] (zero outside [0, T)), x: [32, 4096, 30] f32.
// Per (b,t) the 570-float output row equals the contiguous x span starting at
// (t-9)*30. A pair of rows (t even, t+1) is 1140 floats = 285 float4 units,
// 16B-aligned. Each thread emits exactly one 16B nontemporal store built from
// two float2 loads (a float2 never straddles a row: 570 is even, and both
// lanes of a float2 share one validity predicate since TC is even).

typedef float f32x4 __attribute__((ext_vector_type(4)));

constexpr int B   = 32;
constexpr int T   = 4096;          // power of 2
constexpr int C   = 30;
constexpr int PAD = 9;             // W/2
constexpr int ROW = 570;           // W*C floats per output row
constexpr int TC  = T * C;         // 122880 floats per batch of x
constexpr int PAIR_F4 = 285;       // float4 units per row-pair (1140 floats)
constexpr unsigned NPAIRS = (unsigned)B * (T / 2);   // 65536 row-pairs
constexpr unsigned TOTAL4 = NPAIRS * PAIR_F4;        // 18,662,400 float4 units

__global__ __launch_bounds__(256)
void OverlapTimeWindowLayer_kernel(const float* __restrict__ x,
                                   f32x4* __restrict__ out) {
    const unsigned v = blockIdx.x * 256u + threadIdx.x;   // exact grid, no loop
    const unsigned p = v / PAIR_F4;            // row-pair index (magic-mul div)
    const int u  = (int)(v - p * PAIR_F4);     // float4 unit within pair [0,285)
    const int b  = (int)(p >> 11);             // / (T/2)
    const int tp = (int)(p & 2047);            // pair's first row is t = 2*tp
    const int base = (2 * tp - PAD) * C;       // source offset of row t
    const int e0 = 4 * u;                      // element offset within pair
    const float* xb = x + (unsigned)b * TC;

    // Half-unit h covers pair-elements e0+2h, e0+2h+1. If e >= ROW it belongs
    // to row t+1: source = base + e - (ROW - C)  (since (t+1)'s base = base+C).
    const int s0 = base + e0     - (e0     >= ROW ? (ROW - C) : 0);
    const int s1 = base + e0 + 2 - (e0 + 2 >= ROW ? (ROW - C) : 0);

    float2 lo = make_float2(0.0f, 0.0f);
    float2 hi = make_float2(0.0f, 0.0f);
    if (s0 >= 0 && s0 < TC) lo = *reinterpret_cast<const float2*>(xb + s0);
    if (s1 >= 0 && s1 < TC) hi = *reinterpret_cast<const float2*>(xb + s1);

    f32x4 val;
    val.x = lo.x; val.y = lo.y; val.z = hi.x; val.w = hi.y;
    __builtin_nontemporal_store(val, out + v);
}

extern "C" void kernel_launch(void* const* d_in, const int* in_sizes, int n_in,
                              void* d_out, int out_size, void* d_ws, size_t ws_size,
                              hipStream_t stream) {
    const float* x = (const float*)d_in[0];
    f32x4* out = (f32x4*)d_out;
    const int block = 256;
    const unsigned grid = TOTAL4 / block;      // 72,900 blocks, exact
    OverlapTimeWindowLayer_kernel<<<grid, block, 0, stream>>>(x, out);
}